// Round 2
// baseline (634.825 us; speedup 1.0000x reference)
//
#include <hip/hip_runtime.h>
#include <stdint.h>

typedef __attribute__((ext_vector_type(8))) short bf16x8_t;
typedef __attribute__((ext_vector_type(4))) float f32x4_t;

#define GLOAD_LDS16(gp, lp) __builtin_amdgcn_global_load_lds( \
    (__attribute__((address_space(1))) void*)(void*)(gp),      \
    (__attribute__((address_space(3))) void*)(lp), 16, 0, 0)

__device__ __forceinline__ float bf2f(unsigned short u) {
  union { unsigned int i; float f; } c; c.i = ((unsigned int)u) << 16; return c.f;
}
__device__ __forceinline__ unsigned short f2bf(float f) {
  unsigned int x = __float_as_uint(f);
  unsigned int r = (x + 0x7fffu + ((x >> 16) & 1u)) >> 16;
  return (unsigned short)r;
}
__device__ __forceinline__ float fast_tanh(float x) {
  const float cx = fminf(fmaxf(x, -15.f), 15.f);
  const float e  = __expf(2.f * cx);
  return __fdividef(e - 1.f, e + 1.f);
}

// ---------------- conversion kernels ----------------
// x [N,256] f32 -> xh[:, 0:256] bf16 (row stride 512)
__global__ void cvt_x_kernel(const float* __restrict__ x, unsigned short* __restrict__ xh, int total) {
  int i = (blockIdx.x * blockDim.x + threadIdx.x) * 4;
  if (i >= total) return;
  float4 v = *(const float4*)(x + i);
  int row = i >> 8, col = i & 255;
  ushort4 o;
  o.x = f2bf(v.x); o.y = f2bf(v.y); o.z = f2bf(v.z); o.w = f2bf(v.w);
  *(ushort4*)(xh + (size_t)row * 512 + col) = o;
}

__global__ void cvt_w_kernel(const float* __restrict__ Wg, const float* __restrict__ W1,
                             const float* __restrict__ W2, unsigned short* __restrict__ Wg_b,
                             unsigned short* __restrict__ W1_b, unsigned short* __restrict__ W2_b) {
  int i = (blockIdx.x * blockDim.x + threadIdx.x) * 4; // 0..262140
  const float* src; unsigned short* dst; int off;
  if (i < 65536)              { src = Wg; dst = Wg_b; off = i; }
  else if (i < 65536 + 131072){ src = W1; dst = W1_b; off = i - 65536; }
  else                        { src = W2; dst = W2_b; off = i - (65536 + 131072); }
  float4 v = *(const float4*)(src + off);
  ushort4 o;
  o.x = f2bf(v.x); o.y = f2bf(v.y); o.z = f2bf(v.z); o.w = f2bf(v.w);
  *(ushort4*)(dst + off) = o;
}

// ---------------- graph-structure kernels ----------------
__global__ void count_kernel(const int* __restrict__ edst, int* __restrict__ deg, int E) {
  int i = blockIdx.x * blockDim.x + threadIdx.x;
  if (i < E) atomicAdd(&deg[edst[i]], 1);
}

#define SCAN_T 1024
__global__ void scan_kernel(const int* __restrict__ deg, int* __restrict__ row_ptr,
                            float* __restrict__ dinv, int n) {
  __shared__ int sums[SCAN_T];
  int t = threadIdx.x;
  int chunk = (n + SCAN_T - 1) / SCAN_T;
  int s = t * chunk, e = s + chunk; if (e > n) e = n; if (s > n) s = n;
  int local = 0;
  for (int i = s; i < e; ++i) local += deg[i];
  sums[t] = local;
  __syncthreads();
  for (int off = 1; off < SCAN_T; off <<= 1) {
    int v = sums[t];
    int add = (t >= off) ? sums[t - off] : 0;
    __syncthreads();
    sums[t] = v + add;
    __syncthreads();
  }
  int base = (t > 0) ? sums[t - 1] : 0; // exclusive prefix of this thread's chunk
  for (int i = s; i < e; ++i) {
    row_ptr[i] = base;
    int d = deg[i];
    dinv[i] = rsqrtf((float)(d + 1)); // +1 self loop
    base += d;
  }
  if (t == SCAN_T - 1) row_ptr[n] = base;
}

__global__ void fill_kernel(const int* __restrict__ esrc, const int* __restrict__ edst,
                            const int* __restrict__ row_ptr, int* __restrict__ cursor,
                            int* __restrict__ csr_src, int E) {
  int i = blockIdx.x * blockDim.x + threadIdx.x;
  if (i < E) {
    int d = edst[i];
    int pos = row_ptr[d] + atomicAdd(&cursor[d], 1);
    csr_src[pos] = esrc[i];
  }
}

// ---------------- aggregation: XCD-sharded column slices ----------------
// xws slice-major [8][N][32] bf16 (each slice = 3.2 MB, fits one XCD's 4 MB L2).
// blockIdx.x & 7 = slice -> round-robin dispatch pins each slice to one XCD.
// One wave per (node, slice): halves process alternate edges, 32 lanes x 2B = 64 B/edge.
__global__ __launch_bounds__(256)
void agg_kernel(const unsigned short* __restrict__ xws, const int* __restrict__ csr_src,
                const int* __restrict__ row_ptr, const float* __restrict__ dinv,
                const float* __restrict__ bias, unsigned short* __restrict__ xh, int n) {
  const int tid   = threadIdx.x;
  const int wid   = tid >> 6;
  const int lane  = tid & 63;
  const int slice = blockIdx.x & 7;
  const int node  = (blockIdx.x >> 3) * 4 + wid;
  if (node >= n) return;
  const int c = lane & 31;   // column within slice
  const int h = lane >> 5;   // edge-parity half
  const unsigned short* base = xws + (size_t)slice * n * 32 + c;

  float acc = 0.f;
  const int beg = row_ptr[node], end = row_ptr[node + 1];
  int e = beg + h;
  for (; e + 2 < end; e += 4) {
    const int s0 = csr_src[e];
    const int s1 = csr_src[e + 2];
    const float v0 = bf2f(base[(size_t)s0 * 32]);
    const float v1 = bf2f(base[(size_t)s1 * 32]);
    acc += v0;
    acc += v1;
  }
  if (e < end) acc += bf2f(base[(size_t)csr_src[e] * 32]);
  if (h == 0) acc += bf2f(base[(size_t)node * 32]);  // self loop
  acc += __shfl_xor(acc, 32);

  const float v = fast_tanh(acc * dinv[node] + bias[slice * 32 + c]);
  if (h == 0)
    xh[(size_t)node * 512 + 256 + slice * 32 + c] = f2bf(v);
}

// ---------------- bf16 MFMA GEMM:  C[M,Nout] = A[M,K] @ B[Nout,K]^T ----------------
// 128x128 tile, BK=64, 4 waves (2x2), 16x16x32 MFMA. XOR-swizzled LDS (src-preswizzled).
// OUT_MODE: 0 = f32 row-major, 1 = bf16 row-major, 2 = bf16 slice-major [8][M][32]
template<bool TANH, int OUT_MODE>
__global__ __launch_bounds__(256, 2)
void gemm_bt_kernel(const unsigned short* __restrict__ A, int lda,
                    const unsigned short* __restrict__ B,
                    const float* __restrict__ bias,
                    const float* __restrict__ row_scale,
                    void* __restrict__ Cp, int ldc, int M, int K) {
  __shared__ __align__(16) unsigned short As[128 * 64];
  __shared__ __align__(16) unsigned short Bs[128 * 64];
  const int tid  = threadIdx.x;
  const int lane = tid & 63;
  const int wid  = tid >> 6;
  const int wm = wid & 1, wn = wid >> 1;
  const int tileM = blockIdx.x * 128;
  const int tileN = blockIdx.y * 128;

  const int rowInCh = lane >> 3;               // 0..7
  const int slot    = lane & 7;                // 0..7 (16B slots in a 128B row)
  const int srcOff  = ((slot ^ rowInCh) * 8);  // pre-swizzled source k-offset (elements)

  f32x4_t acc[4][4];
#pragma unroll
  for (int m = 0; m < 4; ++m)
#pragma unroll
    for (int n = 0; n < 4; ++n) acc[m][n] = (f32x4_t){0.f, 0.f, 0.f, 0.f};

  for (int kt = 0; kt < K; kt += 64) {
#pragma unroll
    for (int cc = 0; cc < 4; ++cc) {
      const int c = wid * 4 + cc;            // chunk 0..15, 8 rows each
      const int r = c * 8 + rowInCh;         // 0..127
      const int rA = min(tileM + r, M - 1);  // clamp tail (garbage rows never stored)
      const unsigned short* gA = A + (size_t)rA * lda + (kt + srcOff);
      const unsigned short* gB = B + (size_t)(tileN + r) * K + (kt + srcOff);
      GLOAD_LDS16(gA, As + c * 512 + lane * 8);
      GLOAD_LDS16(gB, Bs + c * 512 + lane * 8);
    }
    __syncthreads();
#pragma unroll
    for (int ks = 0; ks < 2; ++ks) {
      bf16x8_t af[4], bfr[4];
      const int ksl = ks * 4 + (lane >> 4);  // logical 16B slot 0..7
#pragma unroll
      for (int m = 0; m < 4; ++m) {
        const int ra = wm * 64 + m * 16 + (lane & 15);
        af[m]  = *(const bf16x8_t*)(As + ra * 64 + ((ksl ^ (ra & 7)) * 8));
        const int rb = wn * 64 + m * 16 + (lane & 15);
        bfr[m] = *(const bf16x8_t*)(Bs + rb * 64 + ((ksl ^ (rb & 7)) * 8));
      }
#pragma unroll
      for (int m = 0; m < 4; ++m)
#pragma unroll
        for (int n = 0; n < 4; ++n)
          acc[m][n] = __builtin_amdgcn_mfma_f32_16x16x32_bf16(af[m], bfr[n], acc[m][n], 0, 0, 0);
    }
    __syncthreads();
  }

  // epilogue: C[row=(lane>>4)*4+reg][col=lane&15] per fragment
  const int colBase = tileN + wn * 64 + (lane & 15);
  const int rowBase = tileM + wm * 64 + ((lane >> 4) << 2);
#pragma unroll
  for (int n = 0; n < 4; ++n) {
    const int gc = colBase + n * 16;
    const float bv = bias ? bias[gc] : 0.f;
#pragma unroll
    for (int m = 0; m < 4; ++m) {
      const int gr0 = rowBase + m * 16;
#pragma unroll
      for (int r = 0; r < 4; ++r) {
        const int gr = gr0 + r;
        if (gr < M) {
          float v = acc[m][n][r];
          if (row_scale) v *= row_scale[gr];
          v += bv;
          if (TANH) v = fast_tanh(v);
          if (OUT_MODE == 0)      ((float*)Cp)[(size_t)gr * ldc + gc] = v;
          else if (OUT_MODE == 1) ((unsigned short*)Cp)[(size_t)gr * ldc + gc] = f2bf(v);
          else ((unsigned short*)Cp)[((size_t)(gc >> 5) * M + gr) * 32 + (gc & 31)] = f2bf(v);
        }
      }
    }
  }
}

// ---------------- launcher ----------------
extern "C" void kernel_launch(void* const* d_in, const int* in_sizes, int n_in,
                              void* d_out, int out_size, void* d_ws, size_t ws_size,
                              hipStream_t stream) {
  const float* x  = (const float*)d_in[0];
  const int*   ei = (const int*)d_in[1];
  const float* Wg = (const float*)d_in[3];
  const float* bg = (const float*)d_in[4];
  const float* W1 = (const float*)d_in[5];
  const float* b1 = (const float*)d_in[6];
  const float* W2 = (const float*)d_in[7];
  const float* b2 = (const float*)d_in[8];
  float* out = (float*)d_out;

  const int N = in_sizes[0] / 256;
  const int E = in_sizes[1] / 2;
  const int* esrc = ei;
  const int* edst = ei + E;

  // xh = [x_bf16 | x1_bf16]  [N,512] bf16 aliases d_out (51.2 MB; consumed before GEMM3 writes)
  unsigned short* xh = (unsigned short*)d_out;

  uint8_t* p = (uint8_t*)d_ws;
  auto alloc = [&](size_t bytes) { uint8_t* q = p; p += (bytes + 255) & ~(size_t)255; return q; };
  unsigned short* xws  = (unsigned short*)alloc((size_t)N * 256 * 2);  // slice-major [8][N][32]
  unsigned short* h2   = (unsigned short*)alloc((size_t)N * 256 * 2);
  unsigned short* Wg_b = (unsigned short*)alloc(256 * 256 * 2);
  unsigned short* W1_b = (unsigned short*)alloc(256 * 512 * 2);
  unsigned short* W2_b = (unsigned short*)alloc(256 * 256 * 2);
  int*   degcur  = (int*)alloc((size_t)N * 2 * 4);
  int*   deg     = degcur;
  int*   cursor  = degcur + N;
  int*   row_ptr = (int*)alloc(((size_t)N + 1) * 4);
  float* dinv    = (float*)alloc((size_t)N * 4);
  int*   csr     = (int*)alloc((size_t)E * 4);
  (void)ws_size; (void)n_in;

  hipMemsetAsync(degcur, 0, (size_t)N * 2 * 4, stream);

  cvt_x_kernel<<<(N * 256 / 4 + 255) / 256, 256, 0, stream>>>(x, xh, N * 256);
  cvt_w_kernel<<<(262144 / 4) / 256, 256, 0, stream>>>(Wg, W1, W2, Wg_b, W1_b, W2_b);
  count_kernel<<<(E + 255) / 256, 256, 0, stream>>>(edst, deg, E);
  scan_kernel<<<1, SCAN_T, 0, stream>>>(deg, row_ptr, dinv, N);
  fill_kernel<<<(E + 255) / 256, 256, 0, stream>>>(esrc, edst, row_ptr, cursor, csr, E);

  dim3 gemm_grid((N + 127) / 128, 2);
  // GEMM1: xws = dinv[row] * (x @ Wg^T), bf16 slice-major out
  gemm_bt_kernel<false, 2><<<gemm_grid, 256, 0, stream>>>(xh, 512, Wg_b, nullptr, dinv, xws, 256, N, 256);
  // aggregate + bias + tanh -> xh[:, 256:512]; slice = blockIdx.x & 7 (XCD-pinned)
  agg_kernel<<<8 * ((N + 3) / 4), 256, 0, stream>>>(xws, csr, row_ptr, dinv, bg, xh, N);
  // GEMM2: h2 = tanh([x|x1] @ W1^T + b1), bf16 out
  gemm_bt_kernel<true, 1><<<gemm_grid, 256, 0, stream>>>(xh, 512, W1_b, b1, nullptr, h2, 256, N, 512);
  // GEMM3: out = tanh(h2 @ W2^T + b2), f32 out
  gemm_bt_kernel<true, 0><<<gemm_grid, 256, 0, stream>>>(h2, 256, W2_b, b2, nullptr, out, 256, N, 256);
}

// Round 3
// 558.720 us; speedup vs baseline: 1.1362x; 1.1362x over previous
//
#include <hip/hip_runtime.h>
#include <stdint.h>

typedef __attribute__((ext_vector_type(8))) short bf16x8_t;
typedef __attribute__((ext_vector_type(4))) float f32x4_t;

#define GLOAD_LDS16(gp, lp) __builtin_amdgcn_global_load_lds( \
    (__attribute__((address_space(1))) void*)(void*)(gp),      \
    (__attribute__((address_space(3))) void*)(lp), 16, 0, 0)

__device__ __forceinline__ float bf2f(unsigned short u) {
  union { unsigned int i; float f; } c; c.i = ((unsigned int)u) << 16; return c.f;
}
__device__ __forceinline__ unsigned short f2bf(float f) {
  unsigned int x = __float_as_uint(f);
  unsigned int r = (x + 0x7fffu + ((x >> 16) & 1u)) >> 16;
  return (unsigned short)r;
}
__device__ __forceinline__ float fast_tanh(float x) {
  const float cx = fminf(fmaxf(x, -15.f), 15.f);
  const float e  = __expf(2.f * cx);
  return __fdividef(e - 1.f, e + 1.f);
}

// ---------------- conversion kernels ----------------
// x [N,256] f32 -> xh[:, 0:256] bf16 (row stride 512)
__global__ void cvt_x_kernel(const float* __restrict__ x, unsigned short* __restrict__ xh, int total) {
  int i = (blockIdx.x * blockDim.x + threadIdx.x) * 4;
  if (i >= total) return;
  float4 v = *(const float4*)(x + i);
  int row = i >> 8, col = i & 255;
  ushort4 o;
  o.x = f2bf(v.x); o.y = f2bf(v.y); o.z = f2bf(v.z); o.w = f2bf(v.w);
  *(ushort4*)(xh + (size_t)row * 512 + col) = o;
}

__global__ void cvt_w_kernel(const float* __restrict__ Wg, const float* __restrict__ W1,
                             const float* __restrict__ W2, unsigned short* __restrict__ Wg_b,
                             unsigned short* __restrict__ W1_b, unsigned short* __restrict__ W2_b) {
  int i = (blockIdx.x * blockDim.x + threadIdx.x) * 4; // 0..262140
  const float* src; unsigned short* dst; int off;
  if (i < 65536)              { src = Wg; dst = Wg_b; off = i; }
  else if (i < 65536 + 131072){ src = W1; dst = W1_b; off = i - 65536; }
  else                        { src = W2; dst = W2_b; off = i - (65536 + 131072); }
  float4 v = *(const float4*)(src + off);
  ushort4 o;
  o.x = f2bf(v.x); o.y = f2bf(v.y); o.z = f2bf(v.z); o.w = f2bf(v.w);
  *(ushort4*)(dst + off) = o;
}

// ---------------- graph-structure kernels ----------------
__global__ void count_kernel(const int* __restrict__ edst, int* __restrict__ deg, int E) {
  int i = blockIdx.x * blockDim.x + threadIdx.x;
  if (i < E) atomicAdd(&deg[edst[i]], 1);
}

#define SCAN_T 1024
__global__ void scan_kernel(const int* __restrict__ deg, int* __restrict__ row_ptr,
                            float* __restrict__ dinv, int n) {
  __shared__ int sums[SCAN_T];
  int t = threadIdx.x;
  int chunk = (n + SCAN_T - 1) / SCAN_T;
  int s = t * chunk, e = s + chunk; if (e > n) e = n; if (s > n) s = n;
  int local = 0;
  for (int i = s; i < e; ++i) local += deg[i];
  sums[t] = local;
  __syncthreads();
  for (int off = 1; off < SCAN_T; off <<= 1) {
    int v = sums[t];
    int add = (t >= off) ? sums[t - off] : 0;
    __syncthreads();
    sums[t] = v + add;
    __syncthreads();
  }
  int base = (t > 0) ? sums[t - 1] : 0; // exclusive prefix of this thread's chunk
  for (int i = s; i < e; ++i) {
    row_ptr[i] = base;
    int d = deg[i];
    dinv[i] = rsqrtf((float)(d + 1)); // +1 self loop
    base += d;
  }
  if (t == SCAN_T - 1) row_ptr[n] = base;
}

__global__ void fill_kernel(const int* __restrict__ esrc, const int* __restrict__ edst,
                            const int* __restrict__ row_ptr, int* __restrict__ cursor,
                            int* __restrict__ csr_src, int E) {
  int i = blockIdx.x * blockDim.x + threadIdx.x;
  if (i < E) {
    int d = edst[i];
    int pos = row_ptr[d] + atomicAdd(&cursor[d], 1);
    csr_src[pos] = esrc[i];
  }
}

// ---------------- aggregation: XCD-sharded column slices, 8 edges/instruction ----------------
// xws slice-major [8][N][32] bf16 (slice = 3.2 MB -> one XCD's 4 MB L2; blockIdx.x&7 pins it).
// Wave = 8 groups x 8 lanes: group g handles edge e+g, lane-in-group gl loads ushort4
// (cols gl*4..gl*4+3). One gather instruction = 8 edges x 64 B = 512 B.
// Self-loop folded in as virtual edge index 'end' (src=node); tail masked by m.
__global__ __launch_bounds__(256)
void agg_kernel(const unsigned short* __restrict__ xws, const int* __restrict__ csr_src,
                const int* __restrict__ row_ptr, const float* __restrict__ dinv,
                const float* __restrict__ bias, unsigned short* __restrict__ xh, int n) {
  const int tid   = threadIdx.x;
  const int wid   = tid >> 6;
  const int lane  = tid & 63;
  const int slice = blockIdx.x & 7;
  const int node  = (blockIdx.x >> 3) * 4 + wid;
  if (node >= n) return;
  const int g  = lane >> 3;   // edge group 0..7
  const int gl = lane & 7;    // lane in group -> cols gl*4..gl*4+3
  const unsigned short* base = xws + (size_t)slice * n * 32 + gl * 4;

  float a0 = 0.f, a1 = 0.f, a2 = 0.f, a3 = 0.f;
  const int beg = row_ptr[node], end = row_ptr[node + 1];
  for (int e = beg; e <= end; e += 8) {
    const int i2 = e + g;
    const int src = (i2 < end) ? csr_src[i2] : node;   // virtual edge 'end' = self loop
    const float m = (i2 <= end) ? 1.f : 0.f;
    const ushort4 v = *(const ushort4*)(base + (size_t)src * 32);
    a0 += m * bf2f(v.x); a1 += m * bf2f(v.y); a2 += m * bf2f(v.z); a3 += m * bf2f(v.w);
  }
#pragma unroll
  for (int mask = 8; mask < 64; mask <<= 1) {
    a0 += __shfl_xor(a0, mask);
    a1 += __shfl_xor(a1, mask);
    a2 += __shfl_xor(a2, mask);
    a3 += __shfl_xor(a3, mask);
  }
  if (lane < 8) {
    const float di = dinv[node];
    const int c0 = slice * 32 + gl * 4;
    ushort4 o;
    o.x = f2bf(fast_tanh(a0 * di + bias[c0 + 0]));
    o.y = f2bf(fast_tanh(a1 * di + bias[c0 + 1]));
    o.z = f2bf(fast_tanh(a2 * di + bias[c0 + 2]));
    o.w = f2bf(fast_tanh(a3 * di + bias[c0 + 3]));
    *(ushort4*)(xh + (size_t)node * 512 + 256 + c0) = o;
  }
}

// ---------------- bf16 MFMA GEMM:  C[M,Nout] = A[M,K] @ B[Nout,K]^T ----------------
// 128x128 tile, BK=64, 4 waves (2x2), 16x16x32 MFMA. XOR-swizzled LDS (src-preswizzled).
// OUT_MODE: 0 = f32 row-major, 1 = bf16 row-major, 2 = bf16 slice-major [8][M][32]
template<bool TANH, int OUT_MODE>
__global__ __launch_bounds__(256, 2)
void gemm_bt_kernel(const unsigned short* __restrict__ A, int lda,
                    const unsigned short* __restrict__ B,
                    const float* __restrict__ bias,
                    const float* __restrict__ row_scale,
                    void* __restrict__ Cp, int ldc, int M, int K) {
  __shared__ __align__(16) unsigned short As[128 * 64];
  __shared__ __align__(16) unsigned short Bs[128 * 64];
  const int tid  = threadIdx.x;
  const int lane = tid & 63;
  const int wid  = tid >> 6;
  const int wm = wid & 1, wn = wid >> 1;
  const int tileM = blockIdx.x * 128;
  const int tileN = blockIdx.y * 128;

  const int rowInCh = lane >> 3;               // 0..7
  const int slot    = lane & 7;                // 0..7 (16B slots in a 128B row)
  const int srcOff  = ((slot ^ rowInCh) * 8);  // pre-swizzled source k-offset (elements)

  f32x4_t acc[4][4];
#pragma unroll
  for (int m = 0; m < 4; ++m)
#pragma unroll
    for (int n = 0; n < 4; ++n) acc[m][n] = (f32x4_t){0.f, 0.f, 0.f, 0.f};

  for (int kt = 0; kt < K; kt += 64) {
#pragma unroll
    for (int cc = 0; cc < 4; ++cc) {
      const int c = wid * 4 + cc;            // chunk 0..15, 8 rows each
      const int r = c * 8 + rowInCh;         // 0..127
      const int rA = min(tileM + r, M - 1);  // clamp tail (garbage rows never stored)
      const unsigned short* gA = A + (size_t)rA * lda + (kt + srcOff);
      const unsigned short* gB = B + (size_t)(tileN + r) * K + (kt + srcOff);
      GLOAD_LDS16(gA, As + c * 512 + lane * 8);
      GLOAD_LDS16(gB, Bs + c * 512 + lane * 8);
    }
    __syncthreads();
#pragma unroll
    for (int ks = 0; ks < 2; ++ks) {
      bf16x8_t af[4], bfr[4];
      const int ksl = ks * 4 + (lane >> 4);  // logical 16B slot 0..7
#pragma unroll
      for (int m = 0; m < 4; ++m) {
        const int ra = wm * 64 + m * 16 + (lane & 15);
        af[m]  = *(const bf16x8_t*)(As + ra * 64 + ((ksl ^ (ra & 7)) * 8));
        const int rb = wn * 64 + m * 16 + (lane & 15);
        bfr[m] = *(const bf16x8_t*)(Bs + rb * 64 + ((ksl ^ (rb & 7)) * 8));
      }
#pragma unroll
      for (int m = 0; m < 4; ++m)
#pragma unroll
        for (int n = 0; n < 4; ++n)
          acc[m][n] = __builtin_amdgcn_mfma_f32_16x16x32_bf16(af[m], bfr[n], acc[m][n], 0, 0, 0);
    }
    __syncthreads();
  }

  // epilogue: C[row=(lane>>4)*4+reg][col=lane&15] per fragment
  const int colBase = tileN + wn * 64 + (lane & 15);
  const int rowBase = tileM + wm * 64 + ((lane >> 4) << 2);
#pragma unroll
  for (int n = 0; n < 4; ++n) {
    const int gc = colBase + n * 16;
    const float bv = bias ? bias[gc] : 0.f;
#pragma unroll
    for (int m = 0; m < 4; ++m) {
      const int gr0 = rowBase + m * 16;
#pragma unroll
      for (int r = 0; r < 4; ++r) {
        const int gr = gr0 + r;
        if (gr < M) {
          float v = acc[m][n][r];
          if (row_scale) v *= row_scale[gr];
          v += bv;
          if (TANH) v = fast_tanh(v);
          if (OUT_MODE == 0)      ((float*)Cp)[(size_t)gr * ldc + gc] = v;
          else if (OUT_MODE == 1) ((unsigned short*)Cp)[(size_t)gr * ldc + gc] = f2bf(v);
          else ((unsigned short*)Cp)[((size_t)(gc >> 5) * M + gr) * 32 + (gc & 31)] = f2bf(v);
        }
      }
    }
  }
}

// ---------------- launcher ----------------
extern "C" void kernel_launch(void* const* d_in, const int* in_sizes, int n_in,
                              void* d_out, int out_size, void* d_ws, size_t ws_size,
                              hipStream_t stream) {
  const float* x  = (const float*)d_in[0];
  const int*   ei = (const int*)d_in[1];
  const float* Wg = (const float*)d_in[3];
  const float* bg = (const float*)d_in[4];
  const float* b1 = (const float*)d_in[6];
  const float* W1 = (const float*)d_in[5];
  const float* W2 = (const float*)d_in[7];
  const float* b2 = (const float*)d_in[8];
  float* out = (float*)d_out;

  const int N = in_sizes[0] / 256;
  const int E = in_sizes[1] / 2;
  const int* esrc = ei;
  const int* edst = ei + E;

  // xh = [x_bf16 | x1_bf16]  [N,512] bf16 aliases d_out (51.2 MB; consumed before GEMM3 writes)
  unsigned short* xh = (unsigned short*)d_out;

  uint8_t* p = (uint8_t*)d_ws;
  auto alloc = [&](size_t bytes) { uint8_t* q = p; p += (bytes + 255) & ~(size_t)255; return q; };
  unsigned short* xws  = (unsigned short*)alloc((size_t)N * 256 * 2);  // slice-major [8][N][32]
  unsigned short* h2   = (unsigned short*)alloc((size_t)N * 256 * 2);
  unsigned short* Wg_b = (unsigned short*)alloc(256 * 256 * 2);
  unsigned short* W1_b = (unsigned short*)alloc(256 * 512 * 2);
  unsigned short* W2_b = (unsigned short*)alloc(256 * 256 * 2);
  int*   degcur  = (int*)alloc((size_t)N * 2 * 4);
  int*   deg     = degcur;
  int*   cursor  = degcur + N;
  int*   row_ptr = (int*)alloc(((size_t)N + 1) * 4);
  float* dinv    = (float*)alloc((size_t)N * 4);
  int*   csr     = (int*)alloc(((size_t)E + 8) * 4);  // +8 pad: tail loads may touch csr[end..end+7]
  (void)ws_size; (void)n_in;

  hipMemsetAsync(degcur, 0, (size_t)N * 2 * 4, stream);

  cvt_x_kernel<<<(N * 256 / 4 + 255) / 256, 256, 0, stream>>>(x, xh, N * 256);
  cvt_w_kernel<<<(262144 / 4) / 256, 256, 0, stream>>>(Wg, W1, W2, Wg_b, W1_b, W2_b);
  count_kernel<<<(E + 255) / 256, 256, 0, stream>>>(edst, deg, E);
  scan_kernel<<<1, SCAN_T, 0, stream>>>(deg, row_ptr, dinv, N);
  fill_kernel<<<(E + 255) / 256, 256, 0, stream>>>(esrc, edst, row_ptr, cursor, csr, E);

  dim3 gemm_grid((N + 127) / 128, 2);
  // GEMM1: xws = dinv[row] * (x @ Wg^T), bf16 slice-major out
  gemm_bt_kernel<false, 2><<<gemm_grid, 256, 0, stream>>>(xh, 512, Wg_b, nullptr, dinv, xws, 256, N, 256);
  // aggregate + bias + tanh -> xh[:, 256:512]; slice = blockIdx.x & 7 (XCD-pinned)
  agg_kernel<<<8 * ((N + 3) / 4), 256, 0, stream>>>(xws, csr, row_ptr, dinv, bg, xh, N);
  // GEMM2: h2 = tanh([x|x1] @ W1^T + b1), bf16 out
  gemm_bt_kernel<true, 1><<<gemm_grid, 256, 0, stream>>>(xh, 512, W1_b, b1, nullptr, h2, 256, N, 512);
  // GEMM3: out = tanh(h2 @ W2^T + b2), f32 out
  gemm_bt_kernel<true, 0><<<gemm_grid, 256, 0, stream>>>(h2, 256, W2_b, b2, nullptr, out, 256, N, 256);
}

// Round 4
// 520.258 us; speedup vs baseline: 1.2202x; 1.0739x over previous
//
#include <hip/hip_runtime.h>
#include <stdint.h>

typedef __attribute__((ext_vector_type(8))) short bf16x8_t;
typedef __attribute__((ext_vector_type(4))) float f32x4_t;

#define GLOAD_LDS16(gp, lp) __builtin_amdgcn_global_load_lds( \
    (__attribute__((address_space(1))) void*)(void*)(gp),      \
    (__attribute__((address_space(3))) void*)(lp), 16, 0, 0)

__device__ __forceinline__ float bf2f(unsigned short u) {
  union { unsigned int i; float f; } c; c.i = ((unsigned int)u) << 16; return c.f;
}
__device__ __forceinline__ unsigned short f2bf(float f) {
  unsigned int x = __float_as_uint(f);
  unsigned int r = (x + 0x7fffu + ((x >> 16) & 1u)) >> 16;
  return (unsigned short)r;
}
__device__ __forceinline__ float fast_tanh(float x) {
  const float cx = fminf(fmaxf(x, -15.f), 15.f);
  const float e  = __expf(2.f * cx);
  return __fdividef(e - 1.f, e + 1.f);
}

// ---------------- conversion kernels ----------------
__global__ void cvt_x_kernel(const float* __restrict__ x, unsigned short* __restrict__ xh, int total) {
  int i = (blockIdx.x * blockDim.x + threadIdx.x) * 4;
  if (i >= total) return;
  float4 v = *(const float4*)(x + i);
  int row = i >> 8, col = i & 255;
  ushort4 o;
  o.x = f2bf(v.x); o.y = f2bf(v.y); o.z = f2bf(v.z); o.w = f2bf(v.w);
  *(ushort4*)(xh + (size_t)row * 512 + col) = o;
}

__global__ void cvt_w_kernel(const float* __restrict__ Wg, const float* __restrict__ W1,
                             const float* __restrict__ W2, unsigned short* __restrict__ Wg_b,
                             unsigned short* __restrict__ W1_b, unsigned short* __restrict__ W2_b) {
  int i = (blockIdx.x * blockDim.x + threadIdx.x) * 4; // 0..262140
  const float* src; unsigned short* dst; int off;
  if (i < 65536)              { src = Wg; dst = Wg_b; off = i; }
  else if (i < 65536 + 131072){ src = W1; dst = W1_b; off = i - 65536; }
  else                        { src = W2; dst = W2_b; off = i - (65536 + 131072); }
  float4 v = *(const float4*)(src + off);
  ushort4 o;
  o.x = f2bf(v.x); o.y = f2bf(v.y); o.z = f2bf(v.z); o.w = f2bf(v.w);
  *(ushort4*)(dst + off) = o;
}

// zero row N of each slice (gather target for masked-out lanes)
__global__ void zrow_kernel(unsigned short* __restrict__ xws, int n) {
  int t = threadIdx.x; // 256 = 8 slices x 32 cols
  xws[((size_t)(t >> 5) * (n + 1) + n) * 32 + (t & 31)] = 0;
}

// ---------------- graph-structure kernels ----------------
__global__ void count_kernel(const int* __restrict__ edst, int* __restrict__ deg, int E) {
  int i = blockIdx.x * blockDim.x + threadIdx.x;
  if (i < E) atomicAdd(&deg[edst[i]], 1);
}

#define SCAN_T 1024
__global__ void scan_kernel(const int* __restrict__ deg, int* __restrict__ row_ptr,
                            float* __restrict__ dinv, int n) {
  __shared__ int sums[SCAN_T];
  int t = threadIdx.x;
  int chunk = (n + SCAN_T - 1) / SCAN_T;
  int s = t * chunk, e = s + chunk; if (e > n) e = n; if (s > n) s = n;
  int local = 0;
  for (int i = s; i < e; ++i) local += deg[i];
  sums[t] = local;
  __syncthreads();
  for (int off = 1; off < SCAN_T; off <<= 1) {
    int v = sums[t];
    int add = (t >= off) ? sums[t - off] : 0;
    __syncthreads();
    sums[t] = v + add;
    __syncthreads();
  }
  int base = (t > 0) ? sums[t - 1] : 0;
  for (int i = s; i < e; ++i) {
    row_ptr[i] = base;
    int d = deg[i];
    dinv[i] = rsqrtf((float)(d + 1)); // +1 self loop
    base += d;
  }
  if (t == SCAN_T - 1) row_ptr[n] = base;
}

__global__ void fill_kernel(const int* __restrict__ esrc, const int* __restrict__ edst,
                            const int* __restrict__ row_ptr, int* __restrict__ cursor,
                            int* __restrict__ csr_src, int E) {
  int i = blockIdx.x * blockDim.x + threadIdx.x;
  if (i < E) {
    int d = edst[i];
    int pos = row_ptr[d] + atomicAdd(&cursor[d], 1);
    csr_src[pos] = esrc[i];
  }
}

// ---------------- aggregation: XCD-sharded slices, prefetched csr, 8 gathers in flight ----
// xws slice-major [8][N+1][32] bf16; slice s (3.2 MB) lives in XCD-s L2 (blockIdx.x&7 pin).
// Wave = 8 groups x 8 lanes; batch b: group g handles edge base+b*8+g (512 B / instruction).
// csr indices prefetched 64-at-a-time (one coalesced load), redistributed via ds_bpermute.
// Masked-out lanes gather zero row N (no float masks). Self-loop = virtual edge 'end'.
__global__ __launch_bounds__(256)
void agg_kernel(const unsigned short* __restrict__ xws, const int* __restrict__ csr_src,
                const int* __restrict__ row_ptr, const float* __restrict__ dinv,
                const float* __restrict__ bias, unsigned short* __restrict__ xh, int n) {
  const int tid   = threadIdx.x;
  const int wid   = tid >> 6;
  const int lane  = tid & 63;
  const int slice = blockIdx.x & 7;
  const int node  = (blockIdx.x >> 3) * 4 + wid;
  if (node >= n) return;
  const int g   = lane >> 3;        // edge group 0..7
  const int gl4 = (lane & 7) * 4;   // element offset of this lane's 4 cols
  const unsigned short* sbase = xws + (size_t)slice * (n + 1) * 32;
  const int ZROW = n;

  float a0 = 0.f, a1 = 0.f, a2 = 0.f, a3 = 0.f;
  const int beg = row_ptr[node], end = row_ptr[node + 1]; // virtual self edge at 'end'
  for (int base = beg; base <= end; base += 64) {
    const int il = base + lane;
    int pv = csr_src[il];                 // csr padded by 64: safe
    pv = (il == end) ? node : pv;         // fold self-loop at prefetch
    const int rem = end - base;           // wave-uniform
#pragma unroll
    for (int b = 0; b < 8; ++b) {
      const int sv  = __builtin_amdgcn_ds_bpermute(b * 32 + g * 4, pv);
      const int src = (b * 8 + g <= rem) ? sv : ZROW;
      const ushort4 v = *(const ushort4*)(sbase + src * 32 + gl4);
      a0 += bf2f(v.x); a1 += bf2f(v.y); a2 += bf2f(v.z); a3 += bf2f(v.w);
    }
  }
#pragma unroll
  for (int mask = 8; mask < 64; mask <<= 1) {
    a0 += __shfl_xor(a0, mask);
    a1 += __shfl_xor(a1, mask);
    a2 += __shfl_xor(a2, mask);
    a3 += __shfl_xor(a3, mask);
  }
  if (lane < 8) {
    const float di = dinv[node];
    const int c0 = slice * 32 + gl4;
    ushort4 o;
    o.x = f2bf(fast_tanh(a0 * di + bias[c0 + 0]));
    o.y = f2bf(fast_tanh(a1 * di + bias[c0 + 1]));
    o.z = f2bf(fast_tanh(a2 * di + bias[c0 + 2]));
    o.w = f2bf(fast_tanh(a3 * di + bias[c0 + 3]));
    *(ushort4*)(xh + (size_t)node * 512 + 256 + c0) = o;
  }
}

// ---------------- bf16 MFMA GEMM:  C[M,Nout] = A[M,K] @ B[Nout,K]^T ----------------
// OUT_MODE: 0 = f32 row-major, 1 = bf16 row-major, 2 = bf16 slice-major [8][M+1][32]
template<bool TANH, int OUT_MODE>
__global__ __launch_bounds__(256, 2)
void gemm_bt_kernel(const unsigned short* __restrict__ A, int lda,
                    const unsigned short* __restrict__ B,
                    const float* __restrict__ bias,
                    const float* __restrict__ row_scale,
                    void* __restrict__ Cp, int ldc, int M, int K) {
  __shared__ __align__(16) unsigned short As[128 * 64];
  __shared__ __align__(16) unsigned short Bs[128 * 64];
  const int tid  = threadIdx.x;
  const int lane = tid & 63;
  const int wid  = tid >> 6;
  const int wm = wid & 1, wn = wid >> 1;
  const int tileM = blockIdx.x * 128;
  const int tileN = blockIdx.y * 128;

  const int rowInCh = lane >> 3;
  const int slot    = lane & 7;
  const int srcOff  = ((slot ^ rowInCh) * 8);

  f32x4_t acc[4][4];
#pragma unroll
  for (int m = 0; m < 4; ++m)
#pragma unroll
    for (int n = 0; n < 4; ++n) acc[m][n] = (f32x4_t){0.f, 0.f, 0.f, 0.f};

  for (int kt = 0; kt < K; kt += 64) {
#pragma unroll
    for (int cc = 0; cc < 4; ++cc) {
      const int c = wid * 4 + cc;
      const int r = c * 8 + rowInCh;
      const int rA = min(tileM + r, M - 1);
      const unsigned short* gA = A + (size_t)rA * lda + (kt + srcOff);
      const unsigned short* gB = B + (size_t)(tileN + r) * K + (kt + srcOff);
      GLOAD_LDS16(gA, As + c * 512 + lane * 8);
      GLOAD_LDS16(gB, Bs + c * 512 + lane * 8);
    }
    __syncthreads();
#pragma unroll
    for (int ks = 0; ks < 2; ++ks) {
      bf16x8_t af[4], bfr[4];
      const int ksl = ks * 4 + (lane >> 4);
#pragma unroll
      for (int m = 0; m < 4; ++m) {
        const int ra = wm * 64 + m * 16 + (lane & 15);
        af[m]  = *(const bf16x8_t*)(As + ra * 64 + ((ksl ^ (ra & 7)) * 8));
        const int rb = wn * 64 + m * 16 + (lane & 15);
        bfr[m] = *(const bf16x8_t*)(Bs + rb * 64 + ((ksl ^ (rb & 7)) * 8));
      }
#pragma unroll
      for (int m = 0; m < 4; ++m)
#pragma unroll
        for (int n = 0; n < 4; ++n)
          acc[m][n] = __builtin_amdgcn_mfma_f32_16x16x32_bf16(af[m], bfr[n], acc[m][n], 0, 0, 0);
    }
    __syncthreads();
  }

  const int colBase = tileN + wn * 64 + (lane & 15);
  const int rowBase = tileM + wm * 64 + ((lane >> 4) << 2);
#pragma unroll
  for (int n = 0; n < 4; ++n) {
    const int gc = colBase + n * 16;
    const float bv = bias ? bias[gc] : 0.f;
#pragma unroll
    for (int m = 0; m < 4; ++m) {
      const int gr0 = rowBase + m * 16;
#pragma unroll
      for (int r = 0; r < 4; ++r) {
        const int gr = gr0 + r;
        if (gr < M) {
          float v = acc[m][n][r];
          if (row_scale) v *= row_scale[gr];
          v += bv;
          if (TANH) v = fast_tanh(v);
          if (OUT_MODE == 0)      ((float*)Cp)[(size_t)gr * ldc + gc] = v;
          else if (OUT_MODE == 1) ((unsigned short*)Cp)[(size_t)gr * ldc + gc] = f2bf(v);
          else ((unsigned short*)Cp)[((size_t)(gc >> 5) * (M + 1) + gr) * 32 + (gc & 31)] = f2bf(v);
        }
      }
    }
  }
}

// ---------------- launcher ----------------
extern "C" void kernel_launch(void* const* d_in, const int* in_sizes, int n_in,
                              void* d_out, int out_size, void* d_ws, size_t ws_size,
                              hipStream_t stream) {
  const float* x  = (const float*)d_in[0];
  const int*   ei = (const int*)d_in[1];
  const float* Wg = (const float*)d_in[3];
  const float* bg = (const float*)d_in[4];
  const float* W1 = (const float*)d_in[5];
  const float* b1 = (const float*)d_in[6];
  const float* W2 = (const float*)d_in[7];
  const float* b2 = (const float*)d_in[8];
  float* out = (float*)d_out;

  const int N = in_sizes[0] / 256;
  const int E = in_sizes[1] / 2;
  const int* esrc = ei;
  const int* edst = ei + E;

  // xh = [x_bf16 | x1_bf16]  [N,512] bf16 aliases d_out (consumed before GEMM3 writes)
  unsigned short* xh = (unsigned short*)d_out;

  uint8_t* p = (uint8_t*)d_ws;
  auto alloc = [&](size_t bytes) { uint8_t* q = p; p += (bytes + 255) & ~(size_t)255; return q; };
  unsigned short* xws  = (unsigned short*)alloc((size_t)8 * (N + 1) * 32 * 2); // [8][N+1][32]
  unsigned short* h2   = (unsigned short*)alloc((size_t)N * 256 * 2);
  unsigned short* Wg_b = (unsigned short*)alloc(256 * 256 * 2);
  unsigned short* W1_b = (unsigned short*)alloc(256 * 512 * 2);
  unsigned short* W2_b = (unsigned short*)alloc(256 * 256 * 2);
  int*   degcur  = (int*)alloc((size_t)N * 2 * 4);
  int*   deg     = degcur;
  int*   cursor  = degcur + N;
  int*   row_ptr = (int*)alloc(((size_t)N + 1) * 4);
  float* dinv    = (float*)alloc((size_t)N * 4);
  int*   csr     = (int*)alloc(((size_t)E + 64) * 4);  // +64 pad: prefetch overshoot
  (void)ws_size; (void)n_in;

  hipMemsetAsync(degcur, 0, (size_t)N * 2 * 4, stream);

  cvt_x_kernel<<<(N * 256 / 4 + 255) / 256, 256, 0, stream>>>(x, xh, N * 256);
  cvt_w_kernel<<<(262144 / 4) / 256, 256, 0, stream>>>(Wg, W1, W2, Wg_b, W1_b, W2_b);
  zrow_kernel<<<1, 256, 0, stream>>>(xws, N);
  count_kernel<<<(E + 255) / 256, 256, 0, stream>>>(edst, deg, E);
  scan_kernel<<<1, SCAN_T, 0, stream>>>(deg, row_ptr, dinv, N);
  fill_kernel<<<(E + 255) / 256, 256, 0, stream>>>(esrc, edst, row_ptr, cursor, csr, E);

  dim3 gemm_grid((N + 127) / 128, 2);
  // GEMM1: xws = dinv[row] * (x @ Wg^T), bf16 slice-major out (stride N+1)
  gemm_bt_kernel<false, 2><<<gemm_grid, 256, 0, stream>>>(xh, 512, Wg_b, nullptr, dinv, xws, 256, N, 256);
  // aggregate + bias + tanh -> xh[:, 256:512]
  agg_kernel<<<8 * ((N + 3) / 4), 256, 0, stream>>>(xws, csr, row_ptr, dinv, bg, xh, N);
  // GEMM2: h2 = tanh([x|x1] @ W1^T + b1), bf16 out
  gemm_bt_kernel<true, 1><<<gemm_grid, 256, 0, stream>>>(xh, 512, W1_b, b1, nullptr, h2, 256, N, 512);
  // GEMM3: out = tanh(h2 @ W2^T + b2), f32 out
  gemm_bt_kernel<true, 0><<<gemm_grid, 256, 0, stream>>>(h2, 256, W2_b, b2, nullptr, out, 256, N, 256);
}